// Round 8
// baseline (397.714 us; speedup 1.0000x reference)
//
#include <hip/hip_runtime.h>
#include <hip/hip_cooperative_groups.h>
#include <math.h>

namespace cg = cooperative_groups;

#define N_NODES 2048
#define N_EDGES 4096
#define PI_F 3.14159265358979323846f
#define TWO_PI_F 6.28318530717958647692f

__device__ __forceinline__ float shflx(float v, int m) {
    return __shfl_xor(v, m, 64);
}

// ---------------- gate helpers ----------------
// Amplitude index = lane*NA + j. j bits = in-register, lane bits above.
// RY pair semantics: new0 = c*s0 - s*s1 ; new1 = s*s0 + c*s1.

template<int NA, int B>
__device__ __forceinline__ void ry_j(float* a, float c, float s) {
#pragma unroll
    for (int j = 0; j < NA; ++j) {
        if ((j & (1 << B)) == 0) {
            int k = j | (1 << B);
            float x0 = a[j], x1 = a[k];
            a[j] = c * x0 - s * x1;
            a[k] = s * x0 + c * x1;
        }
    }
}

template<int NA, int LB>
__device__ __forceinline__ void ry_l(float* a, float c, float s, int lane) {
    float ss = ((lane >> LB) & 1) ? s : -s;
#pragma unroll
    for (int j = 0; j < NA; ++j) {
        float p = shflx(a[j], 1 << LB);
        a[j] = c * a[j] + ss * p;
    }
}

template<int NA, int BC, int BT>
__device__ __forceinline__ void cx_jj(float* a) {   // pure register rename
#pragma unroll
    for (int j = 0; j < NA; ++j) {
        if ((j & (1 << BC)) && !(j & (1 << BT))) {
            int k = j | (1 << BT);
            float t = a[j]; a[j] = a[k]; a[k] = t;
        }
    }
}

template<int NA, int LC, int BT>
__device__ __forceinline__ void cx_lj(float* a, int lane) {   // cndmask only
    bool sel = ((lane >> LC) & 1) != 0;
#pragma unroll
    for (int j = 0; j < NA; ++j) {
        if ((j & (1 << BT)) == 0) {
            int k = j | (1 << BT);
            float t0 = a[j], t1 = a[k];
            a[j] = sel ? t1 : t0;
            a[k] = sel ? t0 : t1;
        }
    }
}

template<int NA, int LC, int LT>
__device__ __forceinline__ void cx_ll(float* a, int lane) {
    bool sel = ((lane >> LC) & 1) != 0;
#pragma unroll
    for (int j = 0; j < NA; ++j) {
        float p = shflx(a[j], 1 << LT);
        a[j] = sel ? p : a[j];
    }
}

// ---------------- setup: H0 + index extraction + macc zero + theta trig ----------------
// One float4-pair per thread (2M threads): measured HBM-bound (r2/r7).
__global__ __launch_bounds__(256) void k_setup(
        const float* __restrict__ X, const float* __restrict__ Ri,
        const float* __restrict__ Ro, const float* __restrict__ W,
        const float* __restrict__ b, const float* __restrict__ te,
        const float* __restrict__ tn,
        int* __restrict__ send, int* __restrict__ recv, float* __restrict__ H,
        float* __restrict__ maccA, float* __restrict__ maccB,
        float* __restrict__ trig) {
    int tid = blockIdx.x * blockDim.x + threadIdx.x;
    if (tid < N_NODES) {
        float x0 = X[tid*3+0], x1 = X[tid*3+1], x2 = X[tid*3+2];
        float z = x0*W[0] + x1*W[1] + x2*W[2] + b[0];
        float sg = 1.0f / (1.0f + expf(-z));
        H[tid*4+0] = sg * TWO_PI_F;
        H[tid*4+1] = x0; H[tid*4+2] = x1; H[tid*4+3] = x2;
    }
    if (tid < N_NODES * 8) { maccA[tid] = 0.f; maccB[tid] = 0.f; }
    if (tid >= 4096 && tid < 4096 + 15) {        // edge theta trig
        int i = tid - 4096; float s, c;
        sincosf(0.5f * te[i], &s, &c);
        trig[i] = c; trig[16 + i] = s;
    }
    if (tid >= 4224 && tid < 4224 + 23) {        // node theta trig
        int i = tid - 4224; float s, c;
        sincosf(0.5f * tn[i], &s, &c);
        trig[32 + i] = c; trig[56 + i] = s;
    }
    const float4 vi = ((const float4*)Ri)[tid];
    const float4 vo = ((const float4*)Ro)[tid];
    int base = tid * 4;
    int n = base >> 12;             // row (E = 4096)
    int e = base & (N_EDGES - 1);   // col
    if (vi.x != 0.f) recv[e+0] = n;
    if (vi.y != 0.f) recv[e+1] = n;
    if (vi.z != 0.f) recv[e+2] = n;
    if (vi.w != 0.f) recv[e+3] = n;
    if (vo.x != 0.f) send[e+0] = n;
    if (vo.y != 0.f) send[e+1] = n;
    if (vo.z != 0.f) send[e+2] = n;
    if (vo.w != 0.f) send[e+3] = n;
}

// ---------------- edge circuit: n=8, one wave/edge, 4 amps/lane ----------------
// bits [L5 L4 L3 L2 L1 L0 | J1 J0]; wires: w0=L5 w1=L4 w3=L3 w4=L2 w6=L1 w7=L0, w2=J1 w5=J0.
// Measure wire5 = J0. (verified r2-r7)
template<bool SCATTER>
__device__ __forceinline__ void edge_one(
        int e, int lane,
        const float* __restrict__ H, const int* __restrict__ send,
        const int* __restrict__ recv, const float* __restrict__ trig,
        float* __restrict__ out, float* __restrict__ macc) {
    int si = send[e], ri = recv[e];
    float4 hs = ((const float4*)H)[si];
    float4 hr = ((const float4*)H)[ri];
    float B[8] = {hs.x, hs.y, hs.z, hs.w, hr.x, hr.y, hr.z, hr.w};

    float ec[8], es[8];
#pragma unroll
    for (int k = 0; k < 8; ++k) sincosf(0.5f * B[k], &es[k], &ec[k]);

    float lp;
    {
        float f0 = ((lane>>5)&1) ? es[0] : ec[0];
        float f1 = ((lane>>4)&1) ? es[1] : ec[1];
        float f3 = ((lane>>3)&1) ? es[3] : ec[3];
        float f4 = ((lane>>2)&1) ? es[4] : ec[4];
        float f6 = ((lane>>1)&1) ? es[6] : ec[6];
        float f7 = ( lane     &1) ? es[7] : ec[7];
        lp = f0*f1*f3*f4*f6*f7;
    }
    float a[4];
    a[0] = lp;
    a[1] = a[0]*es[5]; a[0] *= ec[5];          // J0 = wire5
    a[2] = a[0]*es[2]; a[3] = a[1]*es[2];      // J1 = wire2
    a[0] *= ec[2];     a[1] *= ec[2];

    const float* tc = trig;        // cos(te/2)
    const float* ts = trig + 16;   // sin(te/2)

    ry_l<4,5>(a, tc[0], ts[0], lane);          // th0 w0
    ry_l<4,4>(a, tc[1], ts[1], lane);          // th1 w1
    cx_ll<4,5,4>(a, lane);                     // cx 0,1
    ry_j<4,1>(a, tc[2], ts[2]);                // th2 w2
    ry_l<4,3>(a, tc[3], ts[3], lane);          // th3 w3
    cx_lj<4,3,1>(a, lane);                     // cx 3,2
    ry_l<4,2>(a, tc[4], ts[4], lane);          // th4 w4
    ry_j<4,0>(a, tc[5], ts[5]);                // th5 w5
    cx_lj<4,2,0>(a, lane);                     // cx 4,5
    ry_l<4,1>(a, tc[6], ts[6], lane);          // th6 w6
    ry_l<4,0>(a, tc[7], ts[7], lane);          // th7 w7
    cx_ll<4,0,1>(a, lane);                     // cx 7,6
    ry_l<4,4>(a, tc[8], ts[8], lane);          // th8 w1
    ry_j<4,1>(a, tc[9], ts[9]);                // th9 w2
    cx_lj<4,4,1>(a, lane);                     // cx 1,2
    ry_j<4,0>(a, tc[10], ts[10]);              // th10 w5
    ry_l<4,1>(a, tc[11], ts[11], lane);        // th11 w6
    cx_lj<4,1,0>(a, lane);                     // cx 6,5
    ry_j<4,1>(a, tc[12], ts[12]);              // th12 w2
    ry_j<4,0>(a, tc[13], ts[13]);              // th13 w5
    cx_jj<4,1,0>(a);                           // cx 2,5
    ry_j<4,0>(a, tc[14], ts[14]);              // th14 w5

    float p = (a[0]*a[0] + a[2]*a[2]) - (a[1]*a[1] + a[3]*a[3]);
#pragma unroll
    for (int m = 32; m; m >>= 1) p += shflx(p, m);
    float ev = (1.0f - p) * 0.5f;

    if (SCATTER) {
        if (lane < 8) {
            float bv = B[0];
            if (lane == 1) bv = B[1]; if (lane == 2) bv = B[2]; if (lane == 3) bv = B[3];
            if (lane == 4) bv = B[4]; if (lane == 5) bv = B[5]; if (lane == 6) bv = B[6];
            if (lane == 7) bv = B[7];
            int idx = (lane < 4) ? (ri*8 + lane) : (si*8 + 4 + (lane & 3));
            atomicAdd(&macc[idx], ev * bv);
        }
    } else {
        if (lane == 0) out[e] = ev;
    }
}

// ---------------- node circuit half: n=12, TWO waves/node, 32 amps/lane ----------------
// (verified r7) Amp index = W(1) | lane(6) | j(5).
// W = w11 (wave parity). Lane: L5=w0 L4=w1 L3=w3 L2=w4 L1=w7 L0=w8.
// Reg:  J4=w2 J3=w5 J2=w6 J1=w9 J0=w10. Measure wire9 = J1 (bit 1 of j).
// W-dependence is a scalar factor until th11; cx(11,10) is parity-local.
// slot = 2-float LDS for this node's pair reduce.
__device__ __forceinline__ void node_half(
        int n, int par, int lane, const float* __restrict__ macc,
        float* __restrict__ H, const float* __restrict__ trig,
        volatile float* slot) {
    float4 m0 = ((const float4*)macc)[n*2];
    float4 m1 = ((const float4*)macc)[n*2+1];
    float4 hv = ((const float4*)H)[n];
    float M[12] = {m0.x, m0.y, m0.z, m0.w, m1.x, m1.y, m1.z, m1.w,
                   hv.x, hv.y, hv.z, hv.w};

    float mc[12], ms[12];
#pragma unroll
    for (int k = 0; k < 12; ++k) sincosf(0.5f * M[k], &ms[k], &mc[k]);

    float lp;
    {
        float f0 = ((lane>>5)&1) ? ms[0] : mc[0];
        float f1 = ((lane>>4)&1) ? ms[1] : mc[1];
        float f3 = ((lane>>3)&1) ? ms[3] : mc[3];
        float f4 = ((lane>>2)&1) ? ms[4] : mc[4];
        float f7 = ((lane>>1)&1) ? ms[7] : mc[7];
        float f8 = ( lane    &1) ? ms[8] : mc[8];
        lp = f0*f1*f3*f4*f7*f8;
    }
    float a[32];
    a[0] = lp;
    {   // doubling over J0=w10, J1=w9, J2=w6, J3=w5, J4=w2
        const int jw[5] = {10, 9, 6, 5, 2};
#pragma unroll
        for (int bnum = 0; bnum < 5; ++bnum) {
            int sz = 1 << bnum;
            float cw = mc[jw[bnum]], sw = ms[jw[bnum]];
#pragma unroll
            for (int k = 0; k < 32; ++k) {
                if (k < sz) {
                    a[k + sz] = a[k] * sw;
                    a[k] *= cw;
                }
            }
        }
    }

    const float* tc = trig + 32;   // cos(tn/2)
    const float* ts = trig + 56;   // sin(tn/2)

    ry_l<32,5>(a, tc[0], ts[0], lane);         // th0 w0
    ry_l<32,4>(a, tc[1], ts[1], lane);         // th1 w1
    cx_ll<32,5,4>(a, lane);                    // cx 0,1
    ry_j<32,4>(a, tc[2], ts[2]);               // th2 w2 (J4)
    ry_l<32,3>(a, tc[3], ts[3], lane);         // th3 w3
    cx_lj<32,3,4>(a, lane);                    // cx 3,2
    ry_l<32,2>(a, tc[4], ts[4], lane);         // th4 w4
    ry_j<32,3>(a, tc[5], ts[5]);               // th5 w5 (J3)
    cx_lj<32,2,3>(a, lane);                    // cx 4,5
    ry_j<32,2>(a, tc[6], ts[6]);               // th6 w6 (J2)
    ry_l<32,1>(a, tc[7], ts[7], lane);         // th7 w7
    cx_lj<32,1,2>(a, lane);                    // cx 7,6
    ry_l<32,0>(a, tc[8], ts[8], lane);         // th8 w8
    ry_j<32,1>(a, tc[9], ts[9]);               // th9 w9 (J1)
    cx_lj<32,0,1>(a, lane);                    // cx 8,9
    ry_j<32,0>(a, tc[10], ts[10]);             // th10 w10 (J0)
    {   // th11 w11 (W): scalar factor, rotated
        float f = par ? (ts[11]*mc[11] + tc[11]*ms[11])
                      : (tc[11]*mc[11] - ts[11]*ms[11]);
#pragma unroll
        for (int j = 0; j < 32; ++j) a[j] *= f;
    }
    if (par) {   // cx 11,10: parity-1 wave swaps J0 pairs
#pragma unroll
        for (int j = 0; j < 32; j += 2) {
            float t = a[j]; a[j] = a[j+1]; a[j+1] = t;
        }
    }
    ry_l<32,4>(a, tc[12], ts[12], lane);       // th12 w1
    ry_j<32,4>(a, tc[13], ts[13]);             // th13 w2
    cx_lj<32,4,4>(a, lane);                    // cx 1,2
    ry_j<32,3>(a, tc[14], ts[14]);             // th14 w5
    ry_j<32,2>(a, tc[15], ts[15]);             // th15 w6
    cx_jj<32,2,3>(a);                          // cx 6,5
    ry_j<32,1>(a, tc[16], ts[16]);             // th16 w9
    ry_j<32,0>(a, tc[17], ts[17]);             // th17 w10
    cx_jj<32,0,1>(a);                          // cx 10,9
    ry_j<32,4>(a, tc[18], ts[18]);             // th18 w2
    ry_j<32,3>(a, tc[19], ts[19]);             // th19 w5
    cx_jj<32,4,3>(a);                          // cx 2,5
    ry_j<32,3>(a, tc[20], ts[20]);             // th20 w5
    ry_j<32,1>(a, tc[21], ts[21]);             // th21 w9
    cx_jj<32,3,1>(a);                          // cx 5,9
    ry_l<32,2>(a, tc[22], ts[22], lane);       // th22 w4

    float p = 0.f;
#pragma unroll
    for (int j = 0; j < 32; ++j) {
        float q = a[j]*a[j];
        p += (j & 2) ? -q : q;
    }
#pragma unroll
    for (int m = 32; m; m >>= 1) p += shflx(p, m);
    if (lane == 0) slot[par] = p;
    __syncthreads();
    if (lane == 0 && par == 0)
        H[n*4+0] = PI_F * (1.0f - (slot[0] + slot[1]));
    __syncthreads();    // slot reusable next trip
}

// ---------------- circuit pipeline: one cooperative kernel, 4 grid syncs ----
// Max live set = node_half's a[32]+trig ~ 75 VGPR -> fits the ~76-80 the
// allocator picks (r3-r6 fusion failure was a[64] ~140 demand vs 76 alloc).
__global__ __launch_bounds__(256) void k_circ(
        const float* __restrict__ trig, const int* __restrict__ send,
        const int* __restrict__ recv, float* __restrict__ H,
        float* __restrict__ maccA, float* __restrict__ maccB,
        float* __restrict__ out) {
    cg::grid_group grid = cg::this_grid();
    __shared__ float part[2][2];
    const int wb   = threadIdx.x >> 6;          // wave in block 0..3
    const int lane = threadIdx.x & 63;
    const int wave = blockIdx.x * 4 + wb;
    const int totWaves = gridDim.x * 4;         // power of 2, divides 4096
    const int trips = N_EDGES / totWaves;       // edges==2*nodes==4096

#pragma unroll 1
    for (int it = 0; it < 2; ++it) {
        float* macc = it ? maccB : maccA;
#pragma unroll 1
        for (int t = 0; t < trips; ++t)
            edge_one<true>(wave + t * totWaves, lane, H, send, recv, trig,
                           nullptr, macc);
        __threadfence();
        grid.sync();
#pragma unroll 1
        for (int t = 0; t < trips; ++t) {
            int idx = wave + t * totWaves;      // idx = n*2 + par
            node_half(idx >> 1, idx & 1, lane, macc, H, trig, part[wb >> 1]);
        }
        __threadfence();
        grid.sync();
    }
#pragma unroll 1
    for (int t = 0; t < trips; ++t)
        edge_one<false>(wave + t * totWaves, lane, H, send, recv, trig,
                        out, nullptr);
}

extern "C" void kernel_launch(void* const* d_in, const int* in_sizes, int n_in,
                              void* d_out, int out_size, void* d_ws, size_t ws_size,
                              hipStream_t stream) {
    const float* X  = (const float*)d_in[0];
    const float* Ri = (const float*)d_in[1];
    const float* Ro = (const float*)d_in[2];
    const float* W  = (const float*)d_in[3];
    const float* b  = (const float*)d_in[4];
    const float* te = (const float*)d_in[5];
    const float* tn = (const float*)d_in[6];
    float* out = (float*)d_out;

    int*   send  = (int*)d_ws;
    int*   recv  = send + N_EDGES;
    float* H     = (float*)(recv + N_EDGES);
    float* maccA = H + N_NODES * 4;
    float* maccB = maccA + N_NODES * 8;
    float* trig  = maccB + N_NODES * 8;

    int total4 = (N_NODES * N_EDGES) / 4;          // one float4-pair per thread
    k_setup<<<total4 / 256, 256, 0, stream>>>(X, Ri, Ro, W, b, te, tn,
                                              send, recv, H, maccA, maccB, trig);

    // cooperative grid: largest power-of-2 block count that is co-resident
    // (so totWaves divides 4096), capped at 1024 blocks = 4096 waves.
    int mb = 2;
    (void)hipOccupancyMaxActiveBlocksPerMultiprocessor(&mb, k_circ, 256, 0);
    if (mb < 1) mb = 1;
    int capacity = mb * 256;        // 256 CUs
    int gridSz = 1024;
    while (gridSz > capacity) gridSz >>= 1;

    void* args[] = {(void*)&trig, (void*)&send, (void*)&recv, (void*)&H,
                    (void*)&maccA, (void*)&maccB, (void*)&out};
    hipLaunchCooperativeKernel((const void*)k_circ, dim3(gridSz), dim3(256),
                               args, 0, stream);
}

// Round 9
// 157.611 us; speedup vs baseline: 2.5234x; 2.5234x over previous
//
#include <hip/hip_runtime.h>
#include <math.h>

#define N_NODES 2048
#define N_EDGES 4096
#define PI_F 3.14159265358979323846f
#define TWO_PI_F 6.28318530717958647692f

__device__ __forceinline__ float shflx(float v, int m) {
    return __shfl_xor(v, m, 64);
}

// ---------------- gate helpers ----------------
// Amplitude index = lane*NA + j. j bits = in-register, lane bits above.
// RY pair semantics: new0 = c*s0 - s*s1 ; new1 = s*s0 + c*s1.

template<int NA, int B>
__device__ __forceinline__ void ry_j(float* a, float c, float s) {
#pragma unroll
    for (int j = 0; j < NA; ++j) {
        if ((j & (1 << B)) == 0) {
            int k = j | (1 << B);
            float x0 = a[j], x1 = a[k];
            a[j] = c * x0 - s * x1;
            a[k] = s * x0 + c * x1;
        }
    }
}

template<int NA, int LB>
__device__ __forceinline__ void ry_l(float* a, float c, float s, int lane) {
    float ss = ((lane >> LB) & 1) ? s : -s;
#pragma unroll
    for (int j = 0; j < NA; ++j) {
        float p = shflx(a[j], 1 << LB);
        a[j] = c * a[j] + ss * p;
    }
}

template<int NA, int BC, int BT>
__device__ __forceinline__ void cx_jj(float* a) {   // pure register rename
#pragma unroll
    for (int j = 0; j < NA; ++j) {
        if ((j & (1 << BC)) && !(j & (1 << BT))) {
            int k = j | (1 << BT);
            float t = a[j]; a[j] = a[k]; a[k] = t;
        }
    }
}

template<int NA, int LC, int BT>
__device__ __forceinline__ void cx_lj(float* a, int lane) {   // cndmask only
    bool sel = ((lane >> LC) & 1) != 0;
#pragma unroll
    for (int j = 0; j < NA; ++j) {
        if ((j & (1 << BT)) == 0) {
            int k = j | (1 << BT);
            float t0 = a[j], t1 = a[k];
            a[j] = sel ? t1 : t0;
            a[k] = sel ? t0 : t1;
        }
    }
}

template<int NA, int LC, int LT>
__device__ __forceinline__ void cx_ll(float* a, int lane) {
    bool sel = ((lane >> LC) & 1) != 0;
#pragma unroll
    for (int j = 0; j < NA; ++j) {
        float p = shflx(a[j], 1 << LT);
        a[j] = sel ? p : a[j];
    }
}

// ---------------- setup: H0 + htrig + indices + macc zero + theta trig ----
// One float4-pair per thread (2M threads): measured HBM-bound (r2/r7).
// htrig[n] = {cos,sin}(0.5*H[n][k]) for k=0..3, as 2 float4s — edges never
// compute trig (libm sincosf was ~half the edge kernel's instructions).
__global__ __launch_bounds__(256) void k_setup(
        const float* __restrict__ X, const float* __restrict__ Ri,
        const float* __restrict__ Ro, const float* __restrict__ W,
        const float* __restrict__ b, const float* __restrict__ te,
        const float* __restrict__ tn,
        int* __restrict__ send, int* __restrict__ recv, float* __restrict__ H,
        float* __restrict__ htrig,
        float* __restrict__ maccA, float* __restrict__ maccB,
        float* __restrict__ trig) {
    int tid = blockIdx.x * blockDim.x + threadIdx.x;
    if (tid < N_NODES) {
        float x0 = X[tid*3+0], x1 = X[tid*3+1], x2 = X[tid*3+2];
        float z = x0*W[0] + x1*W[1] + x2*W[2] + b[0];
        float sg = 1.0f / (1.0f + __expf(-z));
        float h = sg * TWO_PI_F;
        H[tid*4+0] = h;
        H[tid*4+1] = x0; H[tid*4+2] = x1; H[tid*4+3] = x2;
        float c0,s0,c1,s1,c2,s2,c3,s3;
        __sincosf(0.5f*h,  &s0, &c0);
        __sincosf(0.5f*x0, &s1, &c1);
        __sincosf(0.5f*x1, &s2, &c2);
        __sincosf(0.5f*x2, &s3, &c3);
        ((float4*)htrig)[tid*2+0] = make_float4(c0, s0, c1, s1);
        ((float4*)htrig)[tid*2+1] = make_float4(c2, s2, c3, s3);
    }
    if (tid < N_NODES * 8) { maccA[tid] = 0.f; maccB[tid] = 0.f; }
    if (tid >= 4096 && tid < 4096 + 15) {        // edge theta trig
        int i = tid - 4096; float s, c;
        __sincosf(0.5f * te[i], &s, &c);
        trig[i] = c; trig[16 + i] = s;
    }
    if (tid >= 4224 && tid < 4224 + 23) {        // node theta trig
        int i = tid - 4224; float s, c;
        __sincosf(0.5f * tn[i], &s, &c);
        trig[32 + i] = c; trig[56 + i] = s;
    }
    const float4 vi = ((const float4*)Ri)[tid];
    const float4 vo = ((const float4*)Ro)[tid];
    int base = tid * 4;
    int n = base >> 12;             // row (E = 4096)
    int e = base & (N_EDGES - 1);   // col
    if (vi.x != 0.f) recv[e+0] = n;
    if (vi.y != 0.f) recv[e+1] = n;
    if (vi.z != 0.f) recv[e+2] = n;
    if (vi.w != 0.f) recv[e+3] = n;
    if (vo.x != 0.f) send[e+0] = n;
    if (vo.y != 0.f) send[e+1] = n;
    if (vo.z != 0.f) send[e+2] = n;
    if (vo.w != 0.f) send[e+3] = n;
}

// ---------------- edge circuit: n=8, one wave/edge, 4 amps/lane ----------------
// bits [L5 L4 L3 L2 L1 L0 | J1 J0]; wires: w0=L5 w1=L4 w3=L3 w4=L2 w6=L1 w7=L0, w2=J1 w5=J0.
// Measure wire5 = J0. (math verified r2-r8; trig now table-fed, zero sincos)
template<bool SCATTER>
__global__ __launch_bounds__(256) void k_edge(
        const float* __restrict__ H, const float* __restrict__ htrig,
        const int* __restrict__ send, const int* __restrict__ recv,
        const float* __restrict__ trig,
        float* __restrict__ out, float* __restrict__ macc) {
    int e = (blockIdx.x * blockDim.x + threadIdx.x) >> 6;
    int lane = threadIdx.x & 63;
    int si = send[e], ri = recv[e];
    float4 t0 = ((const float4*)htrig)[si*2+0];
    float4 t1 = ((const float4*)htrig)[si*2+1];
    float4 t2 = ((const float4*)htrig)[ri*2+0];
    float4 t3 = ((const float4*)htrig)[ri*2+1];
    float ec[8] = {t0.x, t0.z, t1.x, t1.z, t2.x, t2.z, t3.x, t3.z};
    float es[8] = {t0.y, t0.w, t1.y, t1.w, t2.y, t2.w, t3.y, t3.w};

    float lp;
    {
        float f0 = ((lane>>5)&1) ? es[0] : ec[0];
        float f1 = ((lane>>4)&1) ? es[1] : ec[1];
        float f3 = ((lane>>3)&1) ? es[3] : ec[3];
        float f4 = ((lane>>2)&1) ? es[4] : ec[4];
        float f6 = ((lane>>1)&1) ? es[6] : ec[6];
        float f7 = ( lane     &1) ? es[7] : ec[7];
        lp = f0*f1*f3*f4*f6*f7;
    }
    float a[4];
    a[0] = lp;
    a[1] = a[0]*es[5]; a[0] *= ec[5];          // J0 = wire5
    a[2] = a[0]*es[2]; a[3] = a[1]*es[2];      // J1 = wire2
    a[0] *= ec[2];     a[1] *= ec[2];

    const float* tc = trig;        // cos(te/2)
    const float* ts = trig + 16;   // sin(te/2)

    ry_l<4,5>(a, tc[0], ts[0], lane);          // th0 w0
    ry_l<4,4>(a, tc[1], ts[1], lane);          // th1 w1
    cx_ll<4,5,4>(a, lane);                     // cx 0,1
    ry_j<4,1>(a, tc[2], ts[2]);                // th2 w2
    ry_l<4,3>(a, tc[3], ts[3], lane);          // th3 w3
    cx_lj<4,3,1>(a, lane);                     // cx 3,2
    ry_l<4,2>(a, tc[4], ts[4], lane);          // th4 w4
    ry_j<4,0>(a, tc[5], ts[5]);                // th5 w5
    cx_lj<4,2,0>(a, lane);                     // cx 4,5
    ry_l<4,1>(a, tc[6], ts[6], lane);          // th6 w6
    ry_l<4,0>(a, tc[7], ts[7], lane);          // th7 w7
    cx_ll<4,0,1>(a, lane);                     // cx 7,6
    ry_l<4,4>(a, tc[8], ts[8], lane);          // th8 w1
    ry_j<4,1>(a, tc[9], ts[9]);                // th9 w2
    cx_lj<4,4,1>(a, lane);                     // cx 1,2
    ry_j<4,0>(a, tc[10], ts[10]);              // th10 w5
    ry_l<4,1>(a, tc[11], ts[11], lane);        // th11 w6
    cx_lj<4,1,0>(a, lane);                     // cx 6,5
    ry_j<4,1>(a, tc[12], ts[12]);              // th12 w2
    ry_j<4,0>(a, tc[13], ts[13]);              // th13 w5
    cx_jj<4,1,0>(a);                           // cx 2,5
    ry_j<4,0>(a, tc[14], ts[14]);              // th14 w5

    float p = (a[0]*a[0] + a[2]*a[2]) - (a[1]*a[1] + a[3]*a[3]);
#pragma unroll
    for (int m = 32; m; m >>= 1) p += shflx(p, m);
    float ev = (1.0f - p) * 0.5f;

    if (SCATTER) {
        if (lane < 8) {
            float4 hs = ((const float4*)H)[si];
            float4 hr = ((const float4*)H)[ri];
            float B[8] = {hs.x, hs.y, hs.z, hs.w, hr.x, hr.y, hr.z, hr.w};
            float bv = B[0];
            if (lane == 1) bv = B[1]; if (lane == 2) bv = B[2]; if (lane == 3) bv = B[3];
            if (lane == 4) bv = B[4]; if (lane == 5) bv = B[5]; if (lane == 6) bv = B[6];
            if (lane == 7) bv = B[7];
            int idx = (lane < 4) ? (ri*8 + lane) : (si*8 + 4 + (lane & 3));
            atomicAdd(&macc[idx], ev * bv);
        }
    } else {
        if (lane == 0) out[e] = ev;
    }
}

// ---------------- node circuit: n=12, TWO waves/node, 32 amps/lane ----------------
// (verified r7) Amp index = W(1) | lane(6) | j(5).
// W = w11 (wave parity). Lane: L5=w0 L4=w1 L3=w3 L2=w4 L1=w7 L0=w8.
// Reg:  J4=w2 J3=w5 J2=w6 J1=w9 J0=w10. Measure wire9 = J1 (bit 1 of j).
// W-dependence is a scalar factor until th11; cx(11,10) is parity-local.
__global__ __launch_bounds__(256) void k_node(
        const float* __restrict__ macc, float* __restrict__ H,
        float* __restrict__ htrig, const float* __restrict__ trig) {
    __shared__ float part[2][2];
    int wb   = threadIdx.x >> 6;    // wave in block: 0..3
    int lane = threadIdx.x & 63;
    int pair = wb >> 1;             // node within block: 0..1
    int par  = wb & 1;              // W parity
    int n = blockIdx.x * 2 + pair;

    float4 m0 = ((const float4*)macc)[n*2];
    float4 m1 = ((const float4*)macc)[n*2+1];
    float M[8] = {m0.x, m0.y, m0.z, m0.w, m1.x, m1.y, m1.z, m1.w};

    float mc[12], ms[12];
#pragma unroll
    for (int k = 0; k < 8; ++k) __sincosf(0.5f * M[k], &ms[k], &mc[k]);
    {   // wires 8..11 angles are H[n][0..3]: trig precomputed
        float4 t0 = ((const float4*)htrig)[n*2+0];
        float4 t1 = ((const float4*)htrig)[n*2+1];
        mc[8] = t0.x; ms[8] = t0.y; mc[9]  = t0.z; ms[9]  = t0.w;
        mc[10]= t1.x; ms[10]= t1.y; mc[11] = t1.z; ms[11] = t1.w;
    }

    float lp;
    {
        float f0 = ((lane>>5)&1) ? ms[0] : mc[0];
        float f1 = ((lane>>4)&1) ? ms[1] : mc[1];
        float f3 = ((lane>>3)&1) ? ms[3] : mc[3];
        float f4 = ((lane>>2)&1) ? ms[4] : mc[4];
        float f7 = ((lane>>1)&1) ? ms[7] : mc[7];
        float f8 = ( lane    &1) ? ms[8] : mc[8];
        lp = f0*f1*f3*f4*f7*f8;
    }
    float a[32];
    a[0] = lp;
    {   // doubling over J0=w10, J1=w9, J2=w6, J3=w5, J4=w2
        const int jw[5] = {10, 9, 6, 5, 2};
#pragma unroll
        for (int bnum = 0; bnum < 5; ++bnum) {
            int sz = 1 << bnum;
            float cw = mc[jw[bnum]], sw = ms[jw[bnum]];
#pragma unroll
            for (int k = 0; k < 32; ++k) {
                if (k < sz) {
                    a[k + sz] = a[k] * sw;
                    a[k] *= cw;
                }
            }
        }
    }

    const float* tc = trig + 32;   // cos(tn/2)
    const float* ts = trig + 56;   // sin(tn/2)

    ry_l<32,5>(a, tc[0], ts[0], lane);         // th0 w0
    ry_l<32,4>(a, tc[1], ts[1], lane);         // th1 w1
    cx_ll<32,5,4>(a, lane);                    // cx 0,1
    ry_j<32,4>(a, tc[2], ts[2]);               // th2 w2 (J4)
    ry_l<32,3>(a, tc[3], ts[3], lane);         // th3 w3
    cx_lj<32,3,4>(a, lane);                    // cx 3,2
    ry_l<32,2>(a, tc[4], ts[4], lane);         // th4 w4
    ry_j<32,3>(a, tc[5], ts[5]);               // th5 w5 (J3)
    cx_lj<32,2,3>(a, lane);                    // cx 4,5
    ry_j<32,2>(a, tc[6], ts[6]);               // th6 w6 (J2)
    ry_l<32,1>(a, tc[7], ts[7], lane);         // th7 w7
    cx_lj<32,1,2>(a, lane);                    // cx 7,6
    ry_l<32,0>(a, tc[8], ts[8], lane);         // th8 w8
    ry_j<32,1>(a, tc[9], ts[9]);               // th9 w9 (J1)
    cx_lj<32,0,1>(a, lane);                    // cx 8,9
    ry_j<32,0>(a, tc[10], ts[10]);             // th10 w10 (J0)
    {   // th11 w11 (W): scalar factor, rotated
        float f = par ? (ts[11]*mc[11] + tc[11]*ms[11])
                      : (tc[11]*mc[11] - ts[11]*ms[11]);
#pragma unroll
        for (int j = 0; j < 32; ++j) a[j] *= f;
    }
    if (par) {   // cx 11,10: parity-1 wave swaps J0 pairs
#pragma unroll
        for (int j = 0; j < 32; j += 2) {
            float t = a[j]; a[j] = a[j+1]; a[j+1] = t;
        }
    }
    ry_l<32,4>(a, tc[12], ts[12], lane);       // th12 w1
    ry_j<32,4>(a, tc[13], ts[13]);             // th13 w2
    cx_lj<32,4,4>(a, lane);                    // cx 1,2
    ry_j<32,3>(a, tc[14], ts[14]);             // th14 w5
    ry_j<32,2>(a, tc[15], ts[15]);             // th15 w6
    cx_jj<32,2,3>(a);                          // cx 6,5
    ry_j<32,1>(a, tc[16], ts[16]);             // th16 w9
    ry_j<32,0>(a, tc[17], ts[17]);             // th17 w10
    cx_jj<32,0,1>(a);                          // cx 10,9
    ry_j<32,4>(a, tc[18], ts[18]);             // th18 w2
    ry_j<32,3>(a, tc[19], ts[19]);             // th19 w5
    cx_jj<32,4,3>(a);                          // cx 2,5
    ry_j<32,3>(a, tc[20], ts[20]);             // th20 w5
    ry_j<32,1>(a, tc[21], ts[21]);             // th21 w9
    cx_jj<32,3,1>(a);                          // cx 5,9
    ry_l<32,2>(a, tc[22], ts[22], lane);       // th22 w4

    // <Z> on wire9 = J1 (bit 1 of j)
    float p = 0.f;
#pragma unroll
    for (int j = 0; j < 32; ++j) {
        float q = a[j]*a[j];
        p += (j & 2) ? -q : q;
    }
#pragma unroll
    for (int m = 32; m; m >>= 1) p += shflx(p, m);
    if (lane == 0) part[pair][par] = p;
    __syncthreads();
    if (lane == 0 && par == 0) {
        float h = PI_F * (1.0f - (part[pair][0] + part[pair][1]));
        H[n*4+0] = h;
        float sh, ch;
        __sincosf(0.5f * h, &sh, &ch);
        htrig[n*8+0] = ch;       // keep htrig consistent for the next edge pass
        htrig[n*8+1] = sh;
    }
}

extern "C" void kernel_launch(void* const* d_in, const int* in_sizes, int n_in,
                              void* d_out, int out_size, void* d_ws, size_t ws_size,
                              hipStream_t stream) {
    const float* X  = (const float*)d_in[0];
    const float* Ri = (const float*)d_in[1];
    const float* Ro = (const float*)d_in[2];
    const float* W  = (const float*)d_in[3];
    const float* b  = (const float*)d_in[4];
    const float* te = (const float*)d_in[5];
    const float* tn = (const float*)d_in[6];
    float* out = (float*)d_out;

    int*   send  = (int*)d_ws;
    int*   recv  = send + N_EDGES;
    float* H     = (float*)(recv + N_EDGES);
    float* htrig = H + N_NODES * 4;
    float* ebuf  = htrig + N_NODES * 8;
    float* maccA = ebuf + N_EDGES;
    float* maccB = maccA + N_NODES * 8;
    float* trig  = maccB + N_NODES * 8;

    int total4 = (N_NODES * N_EDGES) / 4;          // one float4-pair per thread
    k_setup<<<total4 / 256, 256, 0, stream>>>(X, Ri, Ro, W, b, te, tn,
                                              send, recv, H, htrig,
                                              maccA, maccB, trig);
    // it 0
    k_edge<true ><<<N_EDGES / 4, 256, 0, stream>>>(H, htrig, send, recv, trig, ebuf, maccA);
    k_node<<<N_NODES / 2, 256, 0, stream>>>(maccA, H, htrig, trig);
    // it 1
    k_edge<true ><<<N_EDGES / 4, 256, 0, stream>>>(H, htrig, send, recv, trig, ebuf, maccB);
    k_node<<<N_NODES / 2, 256, 0, stream>>>(maccB, H, htrig, trig);
    // final edge -> out
    k_edge<false><<<N_EDGES / 4, 256, 0, stream>>>(H, htrig, send, recv, trig, out, nullptr);
}

// Round 10
// 146.974 us; speedup vs baseline: 2.7060x; 1.0724x over previous
//
#include <hip/hip_runtime.h>
#include <math.h>

#define N_NODES 2048
#define N_EDGES 4096
#define PI_F 3.14159265358979323846f
#define TWO_PI_F 6.28318530717958647692f

// xor-shuffle with DPP fast paths (VALU, no DS pipe):
//   mask 1 -> quad_perm [1,0,3,2] (0xB1)
//   mask 2 -> quad_perm [2,3,0,1] (0x4E)
//   mask 8 -> row_ror:8 (0x128): (lane+8)%16 == lane^8 within each 16-row
// masks 4,16,32 stay on ds_bpermute via __shfl_xor.
template<int M>
__device__ __forceinline__ float shflx(float v) {
    if constexpr (M == 1) {
        return __int_as_float(__builtin_amdgcn_mov_dpp(
            __float_as_int(v), 0xB1, 0xF, 0xF, false));
    } else if constexpr (M == 2) {
        return __int_as_float(__builtin_amdgcn_mov_dpp(
            __float_as_int(v), 0x4E, 0xF, 0xF, false));
    } else if constexpr (M == 8) {
        return __int_as_float(__builtin_amdgcn_mov_dpp(
            __float_as_int(v), 0x128, 0xF, 0xF, false));
    } else {
        return __shfl_xor(v, M, 64);
    }
}

__device__ __forceinline__ float wave_sum(float p) {
    p += shflx<32>(p); p += shflx<16>(p); p += shflx<8>(p);
    p += shflx<4>(p);  p += shflx<2>(p);  p += shflx<1>(p);
    return p;
}

// ---------------- gate helpers ----------------
// Amplitude index = lane*NA + j. j bits = in-register, lane bits above.
// RY pair semantics: new0 = c*s0 - s*s1 ; new1 = s*s0 + c*s1.

template<int NA, int B>
__device__ __forceinline__ void ry_j(float* a, float c, float s) {
#pragma unroll
    for (int j = 0; j < NA; ++j) {
        if ((j & (1 << B)) == 0) {
            int k = j | (1 << B);
            float x0 = a[j], x1 = a[k];
            a[j] = c * x0 - s * x1;
            a[k] = s * x0 + c * x1;
        }
    }
}

// MASK = lane-bit mask of the wire
template<int NA, int MASK>
__device__ __forceinline__ void ry_l(float* a, float c, float s, int lane) {
    float ss = (lane & MASK) ? s : -s;
#pragma unroll
    for (int j = 0; j < NA; ++j) {
        float p = shflx<MASK>(a[j]);
        a[j] = c * a[j] + ss * p;
    }
}

template<int NA, int BC, int BT>
__device__ __forceinline__ void cx_jj(float* a) {   // pure register rename
#pragma unroll
    for (int j = 0; j < NA; ++j) {
        if ((j & (1 << BC)) && !(j & (1 << BT))) {
            int k = j | (1 << BT);
            float t = a[j]; a[j] = a[k]; a[k] = t;
        }
    }
}

template<int NA, int MC, int BT>
__device__ __forceinline__ void cx_lj(float* a, int lane) {   // cndmask only
    bool sel = (lane & MC) != 0;
#pragma unroll
    for (int j = 0; j < NA; ++j) {
        if ((j & (1 << BT)) == 0) {
            int k = j | (1 << BT);
            float t0 = a[j], t1 = a[k];
            a[j] = sel ? t1 : t0;
            a[k] = sel ? t0 : t1;
        }
    }
}

template<int NA, int MC, int MT>
__device__ __forceinline__ void cx_ll(float* a, int lane) {
    bool sel = (lane & MC) != 0;
#pragma unroll
    for (int j = 0; j < NA; ++j) {
        float p = shflx<MT>(a[j]);
        a[j] = sel ? p : a[j];
    }
}

// ---------------- setup: H0 + htrig + indices + macc zero + theta trig ----
// One float4-pair per thread (2M threads): measured HBM-bound (r2/r7).
__global__ __launch_bounds__(256) void k_setup(
        const float* __restrict__ X, const float* __restrict__ Ri,
        const float* __restrict__ Ro, const float* __restrict__ W,
        const float* __restrict__ b, const float* __restrict__ te,
        const float* __restrict__ tn,
        int* __restrict__ send, int* __restrict__ recv, float* __restrict__ H,
        float* __restrict__ htrig,
        float* __restrict__ maccA, float* __restrict__ maccB,
        float* __restrict__ trig) {
    int tid = blockIdx.x * blockDim.x + threadIdx.x;
    if (tid < N_NODES) {
        float x0 = X[tid*3+0], x1 = X[tid*3+1], x2 = X[tid*3+2];
        float z = x0*W[0] + x1*W[1] + x2*W[2] + b[0];
        float sg = 1.0f / (1.0f + __expf(-z));
        float h = sg * TWO_PI_F;
        H[tid*4+0] = h;
        H[tid*4+1] = x0; H[tid*4+2] = x1; H[tid*4+3] = x2;
        float c0,s0,c1,s1,c2,s2,c3,s3;
        __sincosf(0.5f*h,  &s0, &c0);
        __sincosf(0.5f*x0, &s1, &c1);
        __sincosf(0.5f*x1, &s2, &c2);
        __sincosf(0.5f*x2, &s3, &c3);
        ((float4*)htrig)[tid*2+0] = make_float4(c0, s0, c1, s1);
        ((float4*)htrig)[tid*2+1] = make_float4(c2, s2, c3, s3);
    }
    if (tid < N_NODES * 8) { maccA[tid] = 0.f; maccB[tid] = 0.f; }
    if (tid >= 4096 && tid < 4096 + 15) {        // edge theta trig
        int i = tid - 4096; float s, c;
        __sincosf(0.5f * te[i], &s, &c);
        trig[i] = c; trig[16 + i] = s;
    }
    if (tid >= 4224 && tid < 4224 + 23) {        // node theta trig
        int i = tid - 4224; float s, c;
        __sincosf(0.5f * tn[i], &s, &c);
        trig[32 + i] = c; trig[56 + i] = s;
    }
    const float4 vi = ((const float4*)Ri)[tid];
    const float4 vo = ((const float4*)Ro)[tid];
    int base = tid * 4;
    int n = base >> 12;             // row (E = 4096)
    int e = base & (N_EDGES - 1);   // col
    if (vi.x != 0.f) recv[e+0] = n;
    if (vi.y != 0.f) recv[e+1] = n;
    if (vi.z != 0.f) recv[e+2] = n;
    if (vi.w != 0.f) recv[e+3] = n;
    if (vo.x != 0.f) send[e+0] = n;
    if (vo.y != 0.f) send[e+1] = n;
    if (vo.z != 0.f) send[e+2] = n;
    if (vo.w != 0.f) send[e+3] = n;
}

// ---------------- edge circuit: n=8, one wave/edge, 4 amps/lane ----------------
// lane masks: w0=32 w1=16 w3=8 w4=4 w6=2 w7=1; regs: w2=J1 w5=J0.
// Measure wire5 = J0. (math verified r2-r9; trig table-fed)
template<bool SCATTER>
__global__ __launch_bounds__(256) void k_edge(
        const float* __restrict__ H, const float* __restrict__ htrig,
        const int* __restrict__ send, const int* __restrict__ recv,
        const float* __restrict__ trig,
        float* __restrict__ out, float* __restrict__ macc) {
    int e = (blockIdx.x * blockDim.x + threadIdx.x) >> 6;
    int lane = threadIdx.x & 63;
    int si = send[e], ri = recv[e];
    float4 t0 = ((const float4*)htrig)[si*2+0];
    float4 t1 = ((const float4*)htrig)[si*2+1];
    float4 t2 = ((const float4*)htrig)[ri*2+0];
    float4 t3 = ((const float4*)htrig)[ri*2+1];
    float ec[8] = {t0.x, t0.z, t1.x, t1.z, t2.x, t2.z, t3.x, t3.z};
    float es[8] = {t0.y, t0.w, t1.y, t1.w, t2.y, t2.w, t3.y, t3.w};

    float lp;
    {
        float f0 = (lane&32) ? es[0] : ec[0];
        float f1 = (lane&16) ? es[1] : ec[1];
        float f3 = (lane& 8) ? es[3] : ec[3];
        float f4 = (lane& 4) ? es[4] : ec[4];
        float f6 = (lane& 2) ? es[6] : ec[6];
        float f7 = (lane& 1) ? es[7] : ec[7];
        lp = f0*f1*f3*f4*f6*f7;
    }
    float a[4];
    a[0] = lp;
    a[1] = a[0]*es[5]; a[0] *= ec[5];          // J0 = wire5
    a[2] = a[0]*es[2]; a[3] = a[1]*es[2];      // J1 = wire2
    a[0] *= ec[2];     a[1] *= ec[2];

    const float* tc = trig;        // cos(te/2)
    const float* ts = trig + 16;   // sin(te/2)

    ry_l<4,32>(a, tc[0], ts[0], lane);         // th0 w0
    ry_l<4,16>(a, tc[1], ts[1], lane);         // th1 w1
    cx_ll<4,32,16>(a, lane);                   // cx 0,1
    ry_j<4,1>(a, tc[2], ts[2]);                // th2 w2
    ry_l<4,8>(a, tc[3], ts[3], lane);          // th3 w3 (DPP)
    cx_lj<4,8,1>(a, lane);                     // cx 3,2
    ry_l<4,4>(a, tc[4], ts[4], lane);          // th4 w4
    ry_j<4,0>(a, tc[5], ts[5]);                // th5 w5
    cx_lj<4,4,0>(a, lane);                     // cx 4,5
    ry_l<4,2>(a, tc[6], ts[6], lane);          // th6 w6 (DPP)
    ry_l<4,1>(a, tc[7], ts[7], lane);          // th7 w7 (DPP)
    cx_ll<4,1,2>(a, lane);                     // cx 7,6 (DPP tgt)
    ry_l<4,16>(a, tc[8], ts[8], lane);         // th8 w1
    ry_j<4,1>(a, tc[9], ts[9]);                // th9 w2
    cx_lj<4,16,1>(a, lane);                    // cx 1,2
    ry_j<4,0>(a, tc[10], ts[10]);              // th10 w5
    ry_l<4,2>(a, tc[11], ts[11], lane);        // th11 w6 (DPP)
    cx_lj<4,2,0>(a, lane);                     // cx 6,5
    ry_j<4,1>(a, tc[12], ts[12]);              // th12 w2
    ry_j<4,0>(a, tc[13], ts[13]);              // th13 w5
    cx_jj<4,1,0>(a);                           // cx 2,5
    ry_j<4,0>(a, tc[14], ts[14]);              // th14 w5

    float p = (a[0]*a[0] + a[2]*a[2]) - (a[1]*a[1] + a[3]*a[3]);
    p = wave_sum(p);
    float ev = (1.0f - p) * 0.5f;

    if (SCATTER) {
        if (lane < 8) {
            float4 hs = ((const float4*)H)[si];
            float4 hr = ((const float4*)H)[ri];
            float B[8] = {hs.x, hs.y, hs.z, hs.w, hr.x, hr.y, hr.z, hr.w};
            float bv = B[0];
            if (lane == 1) bv = B[1]; if (lane == 2) bv = B[2]; if (lane == 3) bv = B[3];
            if (lane == 4) bv = B[4]; if (lane == 5) bv = B[5]; if (lane == 6) bv = B[6];
            if (lane == 7) bv = B[7];
            int idx = (lane < 4) ? (ri*8 + lane) : (si*8 + 4 + (lane & 3));
            atomicAdd(&macc[idx], ev * bv);
        }
    } else {
        if (lane == 0) out[e] = ev;
    }
}

// ---------------- node circuit: n=12, TWO waves/node, 32 amps/lane ----------------
// (verified r7-r9) Amp index = W(1) | lane(6) | j(5).
// W = w11 (parity). Lane masks: w0=32 w1=16 w3=8 w4=4 w7=2 w8=1.
// Regs: J4=w2 J3=w5 J2=w6 J1=w9 J0=w10. Measure wire9 = J1 (bit 1 of j).
// W-dependence is a scalar factor until th11; cx(11,10) is parity-local.
// Lightcone: final 'ry th22 w4' acts after every gate touching w9's cone on a
// disjoint wire -> U†Z9U = Z9 -> dropped.
__global__ __launch_bounds__(256) void k_node(
        const float* __restrict__ macc, float* __restrict__ H,
        float* __restrict__ htrig, const float* __restrict__ trig) {
    __shared__ float part[2][2];
    int wb   = threadIdx.x >> 6;    // wave in block: 0..3
    int lane = threadIdx.x & 63;
    int pair = wb >> 1;             // node within block: 0..1
    int par  = wb & 1;              // W parity
    int n = blockIdx.x * 2 + pair;

    float4 m0 = ((const float4*)macc)[n*2];
    float4 m1 = ((const float4*)macc)[n*2+1];
    float M[8] = {m0.x, m0.y, m0.z, m0.w, m1.x, m1.y, m1.z, m1.w};

    float mc[12], ms[12];
#pragma unroll
    for (int k = 0; k < 8; ++k) __sincosf(0.5f * M[k], &ms[k], &mc[k]);
    {   // wires 8..11 angles are H[n][0..3]: trig precomputed
        float4 t0 = ((const float4*)htrig)[n*2+0];
        float4 t1 = ((const float4*)htrig)[n*2+1];
        mc[8] = t0.x; ms[8] = t0.y; mc[9]  = t0.z; ms[9]  = t0.w;
        mc[10]= t1.x; ms[10]= t1.y; mc[11] = t1.z; ms[11] = t1.w;
    }

    float lp;
    {
        float f0 = (lane&32) ? ms[0] : mc[0];
        float f1 = (lane&16) ? ms[1] : mc[1];
        float f3 = (lane& 8) ? ms[3] : mc[3];
        float f4 = (lane& 4) ? ms[4] : mc[4];
        float f7 = (lane& 2) ? ms[7] : mc[7];
        float f8 = (lane& 1) ? ms[8] : mc[8];
        lp = f0*f1*f3*f4*f7*f8;
    }
    float a[32];
    a[0] = lp;
    {   // doubling over J0=w10, J1=w9, J2=w6, J3=w5, J4=w2
        const int jw[5] = {10, 9, 6, 5, 2};
#pragma unroll
        for (int bnum = 0; bnum < 5; ++bnum) {
            int sz = 1 << bnum;
            float cw = mc[jw[bnum]], sw = ms[jw[bnum]];
#pragma unroll
            for (int k = 0; k < 32; ++k) {
                if (k < sz) {
                    a[k + sz] = a[k] * sw;
                    a[k] *= cw;
                }
            }
        }
    }

    const float* tc = trig + 32;   // cos(tn/2)
    const float* ts = trig + 56;   // sin(tn/2)

    ry_l<32,32>(a, tc[0], ts[0], lane);        // th0 w0
    ry_l<32,16>(a, tc[1], ts[1], lane);        // th1 w1
    cx_ll<32,32,16>(a, lane);                  // cx 0,1
    ry_j<32,4>(a, tc[2], ts[2]);               // th2 w2 (J4)
    ry_l<32,8>(a, tc[3], ts[3], lane);         // th3 w3 (DPP)
    cx_lj<32,8,4>(a, lane);                    // cx 3,2
    ry_l<32,4>(a, tc[4], ts[4], lane);         // th4 w4
    ry_j<32,3>(a, tc[5], ts[5]);               // th5 w5 (J3)
    cx_lj<32,4,3>(a, lane);                    // cx 4,5
    ry_j<32,2>(a, tc[6], ts[6]);               // th6 w6 (J2)
    ry_l<32,2>(a, tc[7], ts[7], lane);         // th7 w7 (DPP)
    cx_lj<32,2,2>(a, lane);                    // cx 7,6
    ry_l<32,1>(a, tc[8], ts[8], lane);         // th8 w8 (DPP)
    ry_j<32,1>(a, tc[9], ts[9]);               // th9 w9 (J1)
    cx_lj<32,1,1>(a, lane);                    // cx 8,9
    ry_j<32,0>(a, tc[10], ts[10]);             // th10 w10 (J0)
    {   // th11 w11 (W): scalar factor, rotated
        float f = par ? (ts[11]*mc[11] + tc[11]*ms[11])
                      : (tc[11]*mc[11] - ts[11]*ms[11]);
#pragma unroll
        for (int j = 0; j < 32; ++j) a[j] *= f;
    }
    if (par) {   // cx 11,10: parity-1 wave swaps J0 pairs
#pragma unroll
        for (int j = 0; j < 32; j += 2) {
            float t = a[j]; a[j] = a[j+1]; a[j+1] = t;
        }
    }
    ry_l<32,16>(a, tc[12], ts[12], lane);      // th12 w1
    ry_j<32,4>(a, tc[13], ts[13]);             // th13 w2
    cx_lj<32,16,4>(a, lane);                   // cx 1,2
    ry_j<32,3>(a, tc[14], ts[14]);             // th14 w5
    ry_j<32,2>(a, tc[15], ts[15]);             // th15 w6
    cx_jj<32,2,3>(a);                          // cx 6,5
    ry_j<32,1>(a, tc[16], ts[16]);             // th16 w9
    ry_j<32,0>(a, tc[17], ts[17]);             // th17 w10
    cx_jj<32,0,1>(a);                          // cx 10,9
    ry_j<32,4>(a, tc[18], ts[18]);             // th18 w2
    ry_j<32,3>(a, tc[19], ts[19]);             // th19 w5
    cx_jj<32,4,3>(a);                          // cx 2,5
    ry_j<32,3>(a, tc[20], ts[20]);             // th20 w5
    ry_j<32,1>(a, tc[21], ts[21]);             // th21 w9
    cx_jj<32,3,1>(a);                          // cx 5,9
    // th22 w4: dropped (outside measurement lightcone of wire 9)

    // <Z> on wire9 = J1 (bit 1 of j)
    float p = 0.f;
#pragma unroll
    for (int j = 0; j < 32; ++j) {
        float q = a[j]*a[j];
        p += (j & 2) ? -q : q;
    }
    p = wave_sum(p);
    if (lane == 0) part[pair][par] = p;
    __syncthreads();
    if (lane == 0 && par == 0) {
        float h = PI_F * (1.0f - (part[pair][0] + part[pair][1]));
        H[n*4+0] = h;
        float sh, ch;
        __sincosf(0.5f * h, &sh, &ch);
        htrig[n*8+0] = ch;       // keep htrig consistent for the next edge pass
        htrig[n*8+1] = sh;
    }
}

extern "C" void kernel_launch(void* const* d_in, const int* in_sizes, int n_in,
                              void* d_out, int out_size, void* d_ws, size_t ws_size,
                              hipStream_t stream) {
    const float* X  = (const float*)d_in[0];
    const float* Ri = (const float*)d_in[1];
    const float* Ro = (const float*)d_in[2];
    const float* W  = (const float*)d_in[3];
    const float* b  = (const float*)d_in[4];
    const float* te = (const float*)d_in[5];
    const float* tn = (const float*)d_in[6];
    float* out = (float*)d_out;

    int*   send  = (int*)d_ws;
    int*   recv  = send + N_EDGES;
    float* H     = (float*)(recv + N_EDGES);
    float* htrig = H + N_NODES * 4;
    float* ebuf  = htrig + N_NODES * 8;
    float* maccA = ebuf + N_EDGES;
    float* maccB = maccA + N_NODES * 8;
    float* trig  = maccB + N_NODES * 8;

    int total4 = (N_NODES * N_EDGES) / 4;          // one float4-pair per thread
    k_setup<<<total4 / 256, 256, 0, stream>>>(X, Ri, Ro, W, b, te, tn,
                                              send, recv, H, htrig,
                                              maccA, maccB, trig);
    // it 0
    k_edge<true ><<<N_EDGES / 4, 256, 0, stream>>>(H, htrig, send, recv, trig, ebuf, maccA);
    k_node<<<N_NODES / 2, 256, 0, stream>>>(maccA, H, htrig, trig);
    // it 1
    k_edge<true ><<<N_EDGES / 4, 256, 0, stream>>>(H, htrig, send, recv, trig, ebuf, maccB);
    k_node<<<N_NODES / 2, 256, 0, stream>>>(maccB, H, htrig, trig);
    // final edge -> out
    k_edge<false><<<N_EDGES / 4, 256, 0, stream>>>(H, htrig, send, recv, trig, out, nullptr);
}